// Round 1
// baseline (269.287 us; speedup 1.0000x reference)
//
#include <hip/hip_runtime.h>
#include <hip/hip_bf16.h>

// Attention: out = softmax_causal((xWq+bq)(xWk+bk)^T / sqrt(D)) (xWv+bv) Wo + bo
// B=4, S=2048, D=1024.  All GEMMs in bf16 MFMA (16x16x32), fp32 accumulate.

typedef __bf16 bf16x8 __attribute__((ext_vector_type(8)));
typedef __bf16 bf16x4 __attribute__((ext_vector_type(4)));
typedef float  f32x4  __attribute__((ext_vector_type(4)));

#define BDIM 1024
#define SDIM 2048
#define BATCH 4

__device__ __forceinline__ void gload_lds16(const void* g, void* l) {
    __builtin_amdgcn_global_load_lds(
        (const __attribute__((address_space(1))) void*)g,
        (__attribute__((address_space(3))) void*)l, 16, 0, 0);
}

// ---------------- fp32 -> bf16 elementwise ----------------
__global__ __launch_bounds__(256) void cvt_f32_bf16(const float* __restrict__ in,
                                                    __bf16* __restrict__ out, long n) {
    long i = ((long)blockIdx.x * 256 + threadIdx.x) * 4;
    if (i + 3 < n) {
        float4 v = *(const float4*)(in + i);
        bf16x4 o;
        o[0] = (__bf16)v.x; o[1] = (__bf16)v.y; o[2] = (__bf16)v.z; o[3] = (__bf16)v.w;
        *(bf16x4*)(out + i) = o;
    }
}

// ---------------- transpose (fp32 or bf16 in) -> bf16 out ----------------
// out[c][r] = in[r][c];  in: R x C row-major, out: C x R row-major.
template <typename Tin>
__global__ __launch_bounds__(256) void transpose_to_bf16(const Tin* __restrict__ in,
                                                         __bf16* __restrict__ out,
                                                         int R, int C, long sIn, long sOut) {
    __shared__ float tile[32][33];
    const long b = blockIdx.z;
    in += b * sIn; out += b * sOut;
    const int r0 = blockIdx.y * 32, c0 = blockIdx.x * 32;
    const int tx = threadIdx.x, ty = threadIdx.y;  // block (32,8)
    #pragma unroll
    for (int j = ty; j < 32; j += 8)
        tile[j][tx] = (float)in[(long)(r0 + j) * C + (c0 + tx)];
    __syncthreads();
    #pragma unroll
    for (int j = ty; j < 32; j += 8)
        out[(long)(c0 + j) * R + (r0 + tx)] = (__bf16)tile[tx][j];
}

// ---------------- BT GEMM: C[M,N] = A[M,K] * B[N,K]^T (+bias) ----------------
// A, B row-major with leading dim K. 128x128 tile, BK=64, 4 waves, 16x16x32 MFMA.
// CSKIP: skip whole tiles strictly above the causal diagonal (N==M tiling of keys).
// CKB:   bound K-loop to (by+1)*128 (PV with causally-zero P beyond the q tile).
template <typename Tout, bool CSKIP, bool CKB>
__global__ __launch_bounds__(256) void gemm_bt(const __bf16* __restrict__ Ag,
                                               const __bf16* __restrict__ Bg,
                                               Tout* __restrict__ Cg,
                                               const float* __restrict__ bias,
                                               int M, int N, int K,
                                               long sA, long sB, long sC) {
    const int bx = blockIdx.x, by = blockIdx.y;
    if (CSKIP && bx > by) return;  // key tile entirely in masked region
    const __bf16* A = Ag + (long)blockIdx.z * sA;
    const __bf16* B = Bg + (long)blockIdx.z * sB;
    Tout* C = Cg + (long)blockIdx.z * sC;

    __shared__ __align__(16) __bf16 As[128 * 64];
    __shared__ __align__(16) __bf16 Bs[128 * 64];

    const int tid = threadIdx.x;
    const int w = tid >> 6, l = tid & 63;
    const int m0 = by * 128, n0 = bx * 128;
    const int wr = (w >> 1) * 64, wc = (w & 1) * 64;   // wave's 64x64 quadrant
    const int fr = l & 15, fk = (l >> 4) * 8;          // fragment row / k-offset
    const int srow = tid >> 3;                          // staging: tid/8 in [0,32)
    const int skk = (tid & 7) * 8;                      // staging k offset
    int kEnd = CKB ? min(K, (by + 1) * 128) : K;

    f32x4 acc[4][4] = {};

    for (int k0 = 0; k0 < kEnd; k0 += 64) {
        #pragma unroll
        for (int it = 0; it < 4; ++it) {
            const int row = it * 32 + srow;
            const __bf16* ga = A + (long)(m0 + row) * K + (k0 + skk);
            const __bf16* gb = B + (long)(n0 + row) * K + (k0 + skk);
            __bf16* la = As + it * 2048 + w * 512;  // wave-uniform base; HW adds lane*16B
            __bf16* lb = Bs + it * 2048 + w * 512;
            gload_lds16(ga, la);
            gload_lds16(gb, lb);
        }
        __syncthreads();  // drains vmcnt (global_load_lds) before ds_read
        #pragma unroll
        for (int ks = 0; ks < 2; ++ks) {
            bf16x8 af[4], bf[4];
            #pragma unroll
            for (int i = 0; i < 4; ++i) {
                af[i] = *(const bf16x8*)(As + (wr + i * 16 + fr) * 64 + ks * 32 + fk);
                bf[i] = *(const bf16x8*)(Bs + (wc + i * 16 + fr) * 64 + ks * 32 + fk);
            }
            #pragma unroll
            for (int i = 0; i < 4; ++i)
                #pragma unroll
                for (int j = 0; j < 4; ++j)
                    acc[i][j] = __builtin_amdgcn_mfma_f32_16x16x32_bf16(af[i], bf[j],
                                                                        acc[i][j], 0, 0, 0);
        }
        __syncthreads();
    }

    // epilogue: C/D layout col = lane&15, row = (lane>>4)*4 + reg  [m89-verified]
    const int rbase = (l >> 4) * 4;
    const int cl = l & 15;
    #pragma unroll
    for (int j = 0; j < 4; ++j) {
        const int col = n0 + wc + j * 16 + cl;
        const float bv = bias ? bias[col] : 0.f;
        #pragma unroll
        for (int i = 0; i < 4; ++i)
            #pragma unroll
            for (int r = 0; r < 4; ++r) {
                const int rowi = m0 + wr + i * 16 + rbase + r;
                C[(long)rowi * N + col] = (Tout)(acc[i][j][r] + bv);
            }
    }
}

// ---------------- causal softmax row kernel ----------------
// P[q][k] = softmax_k(scale * scores[q][k], k <= q), zeros for k > q.
__global__ __launch_bounds__(256) void softmax_causal(const __bf16* __restrict__ scores,
                                                      __bf16* __restrict__ P, float scale) {
    const int q = blockIdx.x;
    const long b = blockIdx.y;
    const __bf16* srow = scores + (b * SDIM + q) * (long)SDIM;
    __bf16* prow = P + (b * SDIM + q) * (long)SDIM;
    const int n = q + 1;
    const int tid = threadIdx.x;
    __shared__ float red[8];

    float vals[8];
    float mx = -1e30f;
    #pragma unroll
    for (int i = 0; i < 8; ++i) {
        const int k = i * 256 + tid;
        const float s = (k < n) ? (float)srow[k] * scale : -1e30f;
        vals[i] = s;
        mx = fmaxf(mx, s);
    }
    #pragma unroll
    for (int o = 32; o > 0; o >>= 1) mx = fmaxf(mx, __shfl_xor(mx, o));
    if ((tid & 63) == 0) red[tid >> 6] = mx;
    __syncthreads();
    mx = fmaxf(fmaxf(red[0], red[1]), fmaxf(red[2], red[3]));

    float p[8];
    float sum = 0.f;
    #pragma unroll
    for (int i = 0; i < 8; ++i) {
        p[i] = __expf(vals[i] - mx);  // masked lanes: exp(-huge) -> 0
        sum += p[i];
    }
    #pragma unroll
    for (int o = 32; o > 0; o >>= 1) sum += __shfl_xor(sum, o);
    if ((tid & 63) == 0) red[4 + (tid >> 6)] = sum;
    __syncthreads();
    sum = red[4] + red[5] + red[6] + red[7];

    const float inv = 1.f / sum;
    #pragma unroll
    for (int i = 0; i < 8; ++i) {
        const int k = i * 256 + tid;
        prow[k] = (__bf16)((k < n) ? p[i] * inv : 0.f);
    }
}

extern "C" void kernel_launch(void* const* d_in, const int* in_sizes, int n_in,
                              void* d_out, int out_size, void* d_ws, size_t ws_size,
                              hipStream_t stream) {
    const float* x  = (const float*)d_in[0];
    // d_in[1] = mask (tril ones) -- causality enforced by index, unused.
    const float* Wq = (const float*)d_in[2];
    const float* bq = (const float*)d_in[3];
    const float* Wk = (const float*)d_in[4];
    const float* bk = (const float*)d_in[5];
    const float* Wv = (const float*)d_in[6];
    const float* bv = (const float*)d_in[7];
    const float* Wo = (const float*)d_in[8];
    const float* bo = (const float*)d_in[9];
    float* out = (float*)d_out;

    char* ws = (char*)d_ws;
    const long MT = (long)BATCH * SDIM;          // 8192 total rows
    const long XE = MT * BDIM;                    // 8,388,608 elements
    __bf16* xb   = (__bf16*)(ws);                 // 16 MiB  [aliased by ctx later]
    __bf16* Wqt  = (__bf16*)(ws + 16777216);
    __bf16* Wkt  = (__bf16*)(ws + 16777216 + 2097152);
    __bf16* Wvt  = (__bf16*)(ws + 16777216 + 2 * 2097152);
    __bf16* Wot  = (__bf16*)(ws + 16777216 + 3 * 2097152);
    __bf16* Qb   = (__bf16*)(ws + 25165824);      // 16 MiB
    __bf16* Kb   = (__bf16*)(ws + 41943040);      // 16 MiB
    __bf16* Vb   = (__bf16*)(ws + 58720256);      // 16 MiB
    __bf16* Vtb  = (__bf16*)(ws + 75497472);      // 16 MiB
    __bf16* Sc   = (__bf16*)(ws + 92274688);      // 32 MiB scores
    __bf16* Pb   = (__bf16*)(ws + 25165824);      // alias Q+K (dead after QK^T)
    __bf16* ctxb = (__bf16*)(ws);                 // alias xb (dead after V proj)

    const long SD = (long)SDIM * BDIM;            // 2,097,152
    const long SS = (long)SDIM * SDIM;            // 4,194,304

    // 1) convert x to bf16
    cvt_f32_bf16<<<dim3((unsigned)(XE / 4 / 256)), 256, 0, stream>>>(x, xb, XE);
    // 2) transpose weights to bf16 [N][K]
    transpose_to_bf16<float><<<dim3(32, 32, 1), dim3(32, 8), 0, stream>>>(Wq, Wqt, BDIM, BDIM, 0, 0);
    transpose_to_bf16<float><<<dim3(32, 32, 1), dim3(32, 8), 0, stream>>>(Wk, Wkt, BDIM, BDIM, 0, 0);
    transpose_to_bf16<float><<<dim3(32, 32, 1), dim3(32, 8), 0, stream>>>(Wv, Wvt, BDIM, BDIM, 0, 0);
    transpose_to_bf16<float><<<dim3(32, 32, 1), dim3(32, 8), 0, stream>>>(Wo, Wot, BDIM, BDIM, 0, 0);
    // 3) projections: Q/K/V = x @ W + b   (M=8192, N=1024, K=1024)
    gemm_bt<__bf16, false, false><<<dim3(8, 64, 1), 256, 0, stream>>>(xb, Wqt, Qb, bq, (int)MT, BDIM, BDIM, 0, 0, 0);
    gemm_bt<__bf16, false, false><<<dim3(8, 64, 1), 256, 0, stream>>>(xb, Wkt, Kb, bk, (int)MT, BDIM, BDIM, 0, 0, 0);
    gemm_bt<__bf16, false, false><<<dim3(8, 64, 1), 256, 0, stream>>>(xb, Wvt, Vb, bv, (int)MT, BDIM, BDIM, 0, 0, 0);
    // 4) V^T per batch: [S,D] -> [D,S]
    transpose_to_bf16<__bf16><<<dim3(32, 64, BATCH), dim3(32, 8), 0, stream>>>(Vb, Vtb, SDIM, BDIM, SD, SD);
    // 5) scores = Q @ K^T  (per batch, causal tile skip), raw logits in bf16
    gemm_bt<__bf16, true, false><<<dim3(16, 16, BATCH), 256, 0, stream>>>(Qb, Kb, Sc, nullptr, SDIM, SDIM, BDIM, SD, SD, SS);
    // 6) causal softmax (scale folded in): P (bf16, zeros above diagonal)
    softmax_causal<<<dim3(SDIM, BATCH), 256, 0, stream>>>(Sc, Pb, 0.03125f);
    // 7) ctx = P @ V  (B operand = V^T, K-loop causally bounded)
    gemm_bt<__bf16, false, true><<<dim3(8, 16, BATCH), 256, 0, stream>>>(Pb, Vtb, ctxb, nullptr, SDIM, BDIM, SDIM, SS, SD, SD);
    // 8) out = ctx @ Wo + bo  (fp32 output)
    gemm_bt<float, false, false><<<dim3(8, 64, 1), 256, 0, stream>>>(ctxb, Wot, out, bo, (int)MT, BDIM, BDIM, 0, 0, 0);
}